// Round 10
// baseline (552.863 us; speedup 1.0000x reference)
//
#include <hip/hip_runtime.h>
#include <stdint.h>

typedef _Float16 f16;
typedef _Float16 f16x8 __attribute__((ext_vector_type(8)));
typedef _Float16 f16x4 __attribute__((ext_vector_type(4)));
typedef float f32x4 __attribute__((ext_vector_type(4)));
typedef int int4v __attribute__((ext_vector_type(4)));
typedef float float4v __attribute__((ext_vector_type(4)));

#define S_LEN 2048
#define D_DIM 64
#define QBLK 128
#define KBLK 64
#define NTHREADS 512
#define KSTEPS 32

// LDS-visibility barrier: no vmcnt drain (T4) — global loads/stores stay in flight.
#define BARRIER() do { \
    asm volatile("s_waitcnt lgkmcnt(0)" ::: "memory"); \
    __builtin_amdgcn_s_barrier(); \
    asm volatile("" ::: "memory"); \
} while (0)

__device__ __forceinline__ f16x8 cvt8(float4v a, float4v b) {
    f16x8 f;
    f[0]=(f16)a[0]; f[1]=(f16)a[1]; f[2]=(f16)a[2]; f[3]=(f16)a[3];
    f[4]=(f16)b[0]; f[5]=(f16)b[1]; f[6]=(f16)b[2]; f[7]=(f16)b[3];
    return f;
}
__device__ __forceinline__ uint32_t f16b(float x) {
    union { f16 h; uint16_t u; } c; c.h = (f16)x; return c.u;
}

// QK^T from swizzled Klds[CUR]: c[ct][r] = S[q=qw0+lr][k = tile*64 + 16ct + 4g + r]
#define QKT_LDS(C, CUR) do { \
    _Pragma("unroll") \
    for (int ct = 0; ct < 4; ++ct) { \
        C[ct] = (f32x4){0.f, 0.f, 0.f, 0.f}; \
        _Pragma("unroll") \
        for (int h = 0; h < 2; ++h) { \
            int rowl = 16 * ct + lr; \
            int idx = (rowl * D_DIM + 8 * g + 32 * h) ^ ((rowl & 7) << 3); \
            f16x8 kf = *(const f16x8*)(&Klds[CUR][idx]); \
            C[ct] = __builtin_amdgcn_mfma_f32_16x16x32_f16(kf, qfrag[h], C[ct], 0, 0, 0); \
        } \
    } \
} while (0)

// mask loads for a kstep PAIR starting at tile TE (even): 8 instrs, each 2 rows x 512B runs
#define MLOAD_PAIR(TE) do { \
    const int* mp = Mg + mat_base + (size_t)(qw0 + mr2) * S_LEN + (TE) * KBLK + mc2; \
    _Pragma("unroll") \
    for (int i = 0; i < 8; ++i) \
        mq[i] = __builtin_nontemporal_load((const int4v*)(mp + (size_t)(2 * i) * S_LEN)); \
} while (0)

// pack 32 bits (8 rows x 4 cols) then redistribute both parities (8 shfls)
#define MBITS_PAIR(BE, BO) do { \
    uint32_t nib32 = 0; \
    _Pragma("unroll") \
    for (int i = 0; i < 8; ++i) { \
        _Pragma("unroll") \
        for (int r = 0; r < 4; ++r) \
            nib32 |= (mq[i][r] != 0 ? 1u : 0u) << (4 * i + r); \
    } \
    const int nsh = 4 * (lr >> 1); \
    BE = 0; BO = 0; \
    _Pragma("unroll") \
    for (int ct = 0; ct < 4; ++ct) { \
        uint32_t v0 = (uint32_t)__shfl((int)nib32, 32 * (lr & 1) + 4 * ct + g, 64); \
        uint32_t v1 = (uint32_t)__shfl((int)nib32, 32 * (lr & 1) + 16 + 4 * ct + g, 64); \
        BE |= ((v0 >> nsh) & 15u) << (4 * ct); \
        BO |= ((v1 >> nsh) & 15u) << (4 * ct); \
    } \
} while (0)

__global__ __launch_bounds__(NTHREADS, 4)
void sdpa_kernel(const float* __restrict__ Qg, const float* __restrict__ Kg,
                 const float* __restrict__ Vg, const int* __restrict__ Mg,
                 float* __restrict__ ProbOut, float* __restrict__ AttnOut)
{
    // LDS: 16 (K dbuf) + 16 (Vt dbuf) + 32 (Astage pair) = 64 KB
    __shared__ f16 Klds[2][KBLK * D_DIM];    // [k][d], rows XOR-swizzled
    __shared__ f16 Vtlds[2][D_DIM * KBLK];   // [d][k'], k'-permuted, rows XOR-swizzled
    __shared__ f16 Astage[8][16 * 128];      // per-wave attn tile [q16][col128], swizzled

    const int tid  = threadIdx.x;
    const int lane = tid & 63;
    const int wq   = tid >> 6;
    const int g    = lane >> 4;
    const int lr   = lane & 15;

    const int wid = ((blockIdx.x & 7) << 7) + (blockIdx.x >> 3);   // XCD swizzle
    const int bh  = wid >> 4;
    const int qb  = wid & 15;
    const int phase = ((bh & 3) << 3) | ((qb & 1) << 2);           // even -> pair-aligned

    const size_t qkv_base = (size_t)bh * S_LEN * D_DIM;
    const size_t mat_base = (size_t)bh * S_LEN * S_LEN;
    const int qw0 = qb * QBLK + wq * 16;

    // 512B-run lane mapping (mask loads + attn flush)
    const int mr2 = lane >> 5;        // row sub 0..1 (instr adds 2i)
    const int mc2 = 4 * (lane & 31);  // col 0..124

    f16x8 qfrag[2];
    {
        const float* qp = Qg + qkv_base + (size_t)(qw0 + lr) * D_DIM + g * 8;
        #pragma unroll
        for (int h = 0; h < 2; ++h)
            qfrag[h] = cvt8(*(const float4v*)(qp + 32 * h),
                            *(const float4v*)(qp + 32 * h + 4));
    }

    const int srow = tid >> 3, scol = (tid & 7) * 8;
    const int sidx = (srow * D_DIM + scol) ^ ((srow & 7) << 3);
    const int vrp  = tid >> 4, vdb = (tid & 15) * 4;
    const int vk   = 2 * vrp;
    const int vkp  = (vk & 3) | (((vk >> 4) & 3) << 2) | (((vk >> 2) & 3) << 4);

    const float* kbase = Kg + qkv_base;
    const float* vbase = Vg + qkv_base;

    uint32_t mbits[16];
    #pragma unroll
    for (int i = 0; i < 16; ++i) mbits[i] = 0u;

    // ============ sweep 1: l = sum(exp(s)); bits -> registers ============
    float lacc[4] = {0.f, 0.f, 0.f, 0.f};
    float4v ka, kb;
    int4v mq[8];

    {   // prologue: K(phase) -> Klds[0]; mask pair 0
        const float* kp = kbase + (size_t)(phase * KBLK + srow) * D_DIM + scol;
        ka = *(const float4v*)kp; kb = *(const float4v*)(kp + 4);
        MLOAD_PAIR(phase);
        *(f16x8*)&Klds[0][sidx] = cvt8(ka, kb);
    }

#define S1E(T) do { \
    BARRIER(); \
    uint32_t bE, bO; \
    MBITS_PAIR(bE, bO); \
    mbits[(T) >> 1] = bE | (bO << 16); \
    { \
        const int tn = ((T) + 1 + phase) & 31; \
        const float* kp = kbase + (size_t)(tn * KBLK + srow) * D_DIM + scol; \
        ka = *(const float4v*)kp; kb = *(const float4v*)(kp + 4); \
    } \
    if ((T) + 2 < KSTEPS) MLOAD_PAIR(((T) + 2 + phase) & 31); \
    f32x4 c[4]; \
    QKT_LDS(c, (T) & 1); \
    _Pragma("unroll") \
    for (int ct = 0; ct < 4; ++ct) { \
        _Pragma("unroll") \
        for (int r = 0; r < 4; ++r) { \
            float s = c[ct][r] * 0.125f; \
            float p = ((bE >> (4 * ct + r)) & 1) ? 0.f : __expf(s); /* |s|<=8 */ \
            lacc[r] += p; \
        } \
    } \
    *(f16x8*)&Klds[((T) & 1) ^ 1][sidx] = cvt8(ka, kb); \
} while (0)

#define S1O(T) do { \
    BARRIER(); \
    if ((T) + 1 < KSTEPS) { \
        const int tn = ((T) + 1 + phase) & 31; \
        const float* kp = kbase + (size_t)(tn * KBLK + srow) * D_DIM + scol; \
        ka = *(const float4v*)kp; kb = *(const float4v*)(kp + 4); \
    } \
    f32x4 c[4]; \
    QKT_LDS(c, (T) & 1); \
    const uint32_t bO = mbits[(T) >> 1] >> 16; \
    _Pragma("unroll") \
    for (int ct = 0; ct < 4; ++ct) { \
        _Pragma("unroll") \
        for (int r = 0; r < 4; ++r) { \
            float s = c[ct][r] * 0.125f; \
            float p = ((bO >> (4 * ct + r)) & 1) ? 0.f : __expf(s); \
            lacc[r] += p; \
        } \
    } \
    if ((T) + 1 < KSTEPS) *(f16x8*)&Klds[((T) & 1) ^ 1][sidx] = cvt8(ka, kb); \
} while (0)

    S1E(0);  S1O(1);  S1E(2);  S1O(3);  S1E(4);  S1O(5);  S1E(6);  S1O(7);
    S1E(8);  S1O(9);  S1E(10); S1O(11); S1E(12); S1O(13); S1E(14); S1O(15);
    S1E(16); S1O(17); S1E(18); S1O(19); S1E(20); S1O(21); S1E(22); S1O(23);
    S1E(24); S1O(25); S1E(26); S1O(27); S1E(28); S1O(29); S1E(30); S1O(31);

    float lsum = (lacc[0] + lacc[1]) + (lacc[2] + lacc[3]);
    lsum += __shfl_xor(lsum, 16, 64);
    lsum += __shfl_xor(lsum, 32, 64);
    const float inv_l = 1.f / lsum;

    // ============ sweep 2: recompute s, stage pair, flush 512B runs, PV ============
    f32x4 acc[4];
    #pragma unroll
    for (int dt = 0; dt < 4; ++dt) acc[dt] = (f32x4){0.f, 0.f, 0.f, 0.f};

    float4v va, vb;
    {   // prologue
        const float* kp = kbase + (size_t)(phase * KBLK + srow) * D_DIM + scol;
        ka = *(const float4v*)kp; kb = *(const float4v*)(kp + 4);
        const float* vp = vbase + (size_t)(phase * KBLK + vk) * D_DIM + vdb;
        va = *(const float4v*)vp; vb = *(const float4v*)(vp + D_DIM);
        *(f16x8*)&Klds[0][sidx] = cvt8(ka, kb);
        #pragma unroll
        for (int j = 0; j < 4; ++j) {
            int d = vdb + j;
            *(uint32_t*)&Vtlds[0][(d * KBLK + vkp) ^ ((d & 7) << 3)] =
                f16b(va[j]) | (f16b(vb[j]) << 16);
        }
    }

#define S2_CORE(T, BITS, PAR) do { \
    f32x4 c[4]; \
    QKT_LDS(c, (T) & 1); \
    f16x4 pa[4]; \
    _Pragma("unroll") \
    for (int ct = 0; ct < 4; ++ct) { \
        _Pragma("unroll") \
        for (int r = 0; r < 4; ++r) { \
            float s = c[ct][r] * 0.125f; \
            float p = ((BITS) >> (4 * ct + r) & 1) ? 0.f : __expf(s); \
            pa[ct][r] = (f16)(p * inv_l); \
        } \
        *(f16x4*)&Astage[wq][(lr * 128 + 64 * (PAR) + 16 * ct + 4 * g) \
                             ^ ((lr & 7) << 3)] = pa[ct]; \
    } \
    _Pragma("unroll") \
    for (int dt = 0; dt < 4; ++dt) { \
        int row = 16 * dt + lr; \
        f16x8 vfA = *(const f16x8*)&Vtlds[(T) & 1][(row * KBLK + 16 * g)     ^ ((lr & 7) << 3)]; \
        f16x8 vfB = *(const f16x8*)&Vtlds[(T) & 1][(row * KBLK + 16 * g + 8) ^ ((lr & 7) << 3)]; \
        acc[dt] = __builtin_amdgcn_mfma_f32_16x16x16f16( \
            pa[0], __builtin_shufflevector(vfA, vfA, 0, 1, 2, 3), acc[dt], 0, 0, 0); \
        acc[dt] = __builtin_amdgcn_mfma_f32_16x16x16f16( \
            pa[1], __builtin_shufflevector(vfA, vfA, 4, 5, 6, 7), acc[dt], 0, 0, 0); \
        acc[dt] = __builtin_amdgcn_mfma_f32_16x16x16f16( \
            pa[2], __builtin_shufflevector(vfB, vfB, 0, 1, 2, 3), acc[dt], 0, 0, 0); \
        acc[dt] = __builtin_amdgcn_mfma_f32_16x16x16f16( \
            pa[3], __builtin_shufflevector(vfB, vfB, 4, 5, 6, 7), acc[dt], 0, 0, 0); \
    } \
} while (0)

#define S2_LOADS(T) do { \
    if ((T) + 1 < KSTEPS) { \
        const int tn = ((T) + 1 + phase) & 31; \
        const float* kp = kbase + (size_t)(tn * KBLK + srow) * D_DIM + scol; \
        ka = *(const float4v*)kp; kb = *(const float4v*)(kp + 4); \
        const float* vp = vbase + (size_t)(tn * KBLK + vk) * D_DIM + vdb; \
        va = *(const float4v*)vp; vb = *(const float4v*)(vp + D_DIM); \
    } \
} while (0)

#define S2_STAGE(T) do { \
    if ((T) + 1 < KSTEPS) { \
        *(f16x8*)&Klds[((T) & 1) ^ 1][sidx] = cvt8(ka, kb); \
        _Pragma("unroll") \
        for (int j = 0; j < 4; ++j) { \
            int d = vdb + j; \
            *(uint32_t*)&Vtlds[((T) & 1) ^ 1][(d * KBLK + vkp) ^ ((d & 7) << 3)] = \
                f16b(va[j]) | (f16b(vb[j]) << 16); \
        } \
    } \
} while (0)

// pair flush: 8 instrs, each 2 rows x 512B contiguous f32 row-segments
#define FLUSH_PAIR(TE) do { \
    const int t0 = ((TE) + phase) & 31; \
    _Pragma("unroll") \
    for (int i = 0; i < 8; ++i) { \
        int R = 2 * i + mr2; \
        f16x4 a = *(const f16x4*)&Astage[wq][(R * 128 + mc2) ^ ((R & 7) << 3)]; \
        float4v o; o[0]=(float)a[0]; o[1]=(float)a[1]; o[2]=(float)a[2]; o[3]=(float)a[3]; \
        __builtin_nontemporal_store(o, (float4v*)(AttnOut + mat_base + \
            (size_t)(qw0 + R) * S_LEN + t0 * KBLK + mc2)); \
    } \
} while (0)

#define S2E(T) do { \
    BARRIER(); \
    S2_LOADS(T); \
    S2_CORE(T, mbits[(T) >> 1] & 0xffffu, 0); \
    S2_STAGE(T); \
} while (0)

#define S2O(T) do { \
    BARRIER(); \
    S2_LOADS(T); \
    S2_CORE(T, mbits[(T) >> 1] >> 16, 1); \
    FLUSH_PAIR((T) - 1); \
    S2_STAGE(T); \
} while (0)

    S2E(0);  S2O(1);  S2E(2);  S2O(3);  S2E(4);  S2O(5);  S2E(6);  S2O(7);
    S2E(8);  S2O(9);  S2E(10); S2O(11); S2E(12); S2O(13); S2E(14); S2O(15);
    S2E(16); S2O(17); S2E(18); S2O(19); S2E(20); S2O(21); S2E(22); S2O(23);
    S2E(24); S2O(25); S2E(26); S2O(27); S2E(28); S2O(29); S2E(30); S2O(31);

    // epilogue: prob (already normalized; C/D layout col=lr, row=4g+r)
    #pragma unroll
    for (int dt = 0; dt < 4; ++dt) {
        #pragma unroll
        for (int r = 0; r < 4; ++r) {
            int qrow = qw0 + 4 * g + r;
            ProbOut[qkv_base + (size_t)qrow * D_DIM + 16 * dt + lr] = acc[dt][r];
        }
    }
}

extern "C" void kernel_launch(void* const* d_in, const int* in_sizes, int n_in,
                              void* d_out, int out_size, void* d_ws, size_t ws_size,
                              hipStream_t stream)
{
    const float* Q = (const float*)d_in[0];
    const float* K = (const float*)d_in[1];
    const float* V = (const float*)d_in[2];
    const int*   M = (const int*)d_in[3];

    float* prob = (float*)d_out;                          // [4,16,2048,64]
    float* attn = prob + (size_t)4 * 16 * 2048 * 64;      // [4,16,2048,2048]

    dim3 grid(64 * (S_LEN / QBLK));   // 1024
    dim3 block(NTHREADS);
    sdpa_kernel<<<grid, block, 0, stream>>>(Q, K, V, M, prob, attn);
}